// Round 11
// baseline (1436.302 us; speedup 1.0000x reference)
//
#include <hip/hip_runtime.h>

// PositiveWaveFunction: 32-step tanh RNN, batch 8192, hidden 1024.
// R11: R7 (763us proven: 128x256 block, 8 waves 2x4, BK=64, 3-buffer A-LDS
// rotation with counted-vmcnt boundaries) + B (=W) in REGISTERS instead of
// LDS. W is L2-resident; each wave gathers its own B frags (double-set
// bA/bB, depth-1 prefetch, same addressing R10 refcheck'd) while keeping
// 2 waves/SIMD so gather latency is covered (R10's 1-wave/SIMD failure).
// LDS traffic per K-tile drops 176KB -> 80KB (-55%). Boundary = vmcnt(2):
// A(t+1)[2] + B(t+1)[8] drained, A(t+2)[2] still in flight.

typedef __bf16 bf16;
typedef __bf16 bf16x8 __attribute__((ext_vector_type(8)));
typedef float  f32x4  __attribute__((ext_vector_type(4)));

#define HID   1024
#define BATCH 8192
#define NSPIN 32

#define AS1 __attribute__((address_space(1)))
#define AS3 __attribute__((address_space(3)))

__device__ __forceinline__ float tanh_fast(float x) {
    float ax = fabsf(x);
    float t  = __expf(-2.0f * ax);                       // (0,1], no overflow
    float r  = (1.0f - t) * __builtin_amdgcn_rcpf(1.0f + t);
    return __builtin_copysignf(r, x);
}

// ---------------- prep kernels ----------------

__global__ void prep1(const float* __restrict__ din, const float* __restrict__ Wih,
                      const float* __restrict__ Whh, const float* __restrict__ bih,
                      const float* __restrict__ bhh,
                      bf16* __restrict__ Wbf, float* __restrict__ u0, float* __restrict__ u1,
                      unsigned int* __restrict__ words, float* __restrict__ fact) {
    long idx = (long)blockIdx.x * blockDim.x + threadIdx.x;
    long stride = (long)gridDim.x * blockDim.x;
    for (long i = idx; i < (long)HID * HID; i += stride) Wbf[i] = (bf16)Whh[i];
    for (long i = idx; i < HID; i += stride) {
        u0[i] = Wih[i * 2 + 0] + bih[i] + bhh[i];
        u1[i] = Wih[i * 2 + 1] + bih[i] + bhh[i];
    }
    for (long b = idx; b < BATCH; b += stride) {
        unsigned int wv = 0;
        for (int j = 0; j < 31; ++j)
            wv |= (din[((long)j * BATCH + b) * 2 + 1] != 0.0f ? 1u : 0u) << j;
        words[b] = wv;
    }
    if (idx == 0) {  // factorials: float64 cumprod cast to float32, like reference
        double f = 1.0; fact[0] = 1.0f;
        for (int k = 1; k <= NSPIN; ++k) { f *= k; fact[k] = (float)f; }
    }
}

// single block: h after step 0 (identical for all batch rows) + its logits
__global__ void prep2(const float* __restrict__ u0, const float* __restrict__ Wlin,
                      const float* __restrict__ blin,
                      bf16* __restrict__ hrow, float* __restrict__ l0s) {
    __shared__ float red0[16], red1[16];
    int t = threadIdx.x;  // 0..1023
    float hv = tanh_fast(u0[t]);
    hrow[t] = (bf16)hv;
    float s0 = hv * Wlin[t], s1 = hv * Wlin[HID + t];
    #pragma unroll
    for (int off = 1; off < 64; off <<= 1) {
        s0 += __shfl_xor(s0, off, 64);
        s1 += __shfl_xor(s1, off, 64);
    }
    if ((t & 63) == 0) { red0[t >> 6] = s0; red1[t >> 6] = s1; }
    __syncthreads();
    if (t == 0) {
        float a = blin[0], b = blin[1];
        for (int i = 0; i < 16; ++i) { a += red0[i]; b += red1[i]; }
        l0s[0] = a; l0s[1] = b;
    }
}

// broadcast hrow to all 8192 rows of the ping buffer
__global__ void fillh(const bf16* __restrict__ hrow, bf16* __restrict__ hping) {
    const bf16x8* src = (const bf16x8*)hrow;   // 128 vectors per row
    bf16x8* dst = (bf16x8*)hping;
    long n8 = (long)BATCH * HID / 8;
    for (long v = (long)blockIdx.x * blockDim.x + threadIdx.x; v < n8;
         v += (long)gridDim.x * blockDim.x)
        dst[v] = src[v & 127];
}

// ---------------- main recurrence GEMM ----------------
// Z = h_in @ W_hh^T ; z += (bit ? u1 : u0) ; h_out = tanh(z) (bf16)
// partial logits per wave-column -> plog[31][8192][16][2]
// Tile 128x256, BK=64, 8 waves (2x4 of 64x64), 16x16x32 bf16 MFMA.
// A: LDS 3-buffer rotation (XOR swizzle, counted vmcnt). B: global->reg,
// double-set prefetch depth 1.

__global__ __launch_bounds__(512, 2) void gemm_step(
        const bf16* __restrict__ hin, bf16* __restrict__ hout,
        const bf16* __restrict__ Wbf,
        const float* __restrict__ u0, const float* __restrict__ u1,
        const unsigned int* __restrict__ words, int sbit,
        const float* __restrict__ Wlin,
        float* __restrict__ plog_s) {
    __shared__ __align__(16) bf16 sA0[128 * 64];
    __shared__ __align__(16) bf16 sA1[128 * 64];
    __shared__ __align__(16) bf16 sA2[128 * 64];

    const int tid = threadIdx.x;
    const int w = tid >> 6, l = tid & 63;
    const long rowM = (long)blockIdx.x * 128;
    const int  colN = blockIdx.y * 256;

    const int wr = w >> 2, wc = w & 3;      // 2x4 wave grid (64x64 tiles)
    const int fr = l & 15, fq = l >> 4;     // fragment lane coords

    f32x4 acc[4][4] = {};
    bf16x8 bSetA[8], bSetB[8];              // B frag double-set (n*2+kk)

    // staging lane decomposition: 8 rows x 8 chunks per issue
    const int lrow = l >> 3;                 // 0..7
    const int lchk = l & 7;                  // 0..7 (16B chunk)

    // B lane base: W row (output col) = colN + wc*64 + fr, elems fq*8..
    const bf16* gB = Wbf + (long)(colN + wc * 64 + fr) * HID + fq * 8;

// stage A rows (2 loads/wave, 8 waves cover 128 rows), source pre-permuted
// so linear LDS dest == XOR-swizzled layout
#define STG_A(SA, KT) do {                                                                   \
    _Pragma("unroll")                                                                        \
    for (int i = 0; i < 2; ++i) {                                                            \
        const int r_ = w * 16 + i * 8 + lrow;                                                \
        const int sc_ = (lchk ^ (r_ & 7)) * 8;                                               \
        __builtin_amdgcn_global_load_lds(                                                    \
            (const AS1 void*)(hin + (rowM + r_) * HID + (KT) * 64 + sc_),                    \
            (AS3 void*)(&SA[(w * 16 + i * 8) * 64]), 16, 0, 0);                              \
    }                                                                                        \
} while (0)

// B frags global->reg: 8 loads (n=0..3, kk=0..1)
#define LD_B(BS, KT) do {                                                                    \
    _Pragma("unroll")                                                                        \
    for (int n = 0; n < 4; ++n)                                                              \
        _Pragma("unroll")                                                                    \
        for (int kk = 0; kk < 2; ++kk)                                                       \
            BS[n * 2 + kk] = *(const bf16x8*)(gB + (long)n * 16 * HID + (KT) * 64 + kk * 32);\
} while (0)

#define RD_A(AF, SA, KK) do {                                                                \
    _Pragma("unroll")                                                                        \
    for (int m = 0; m < 4; ++m) {                                                            \
        const int ra_ = wr * 64 + m * 16 + fr;                                               \
        AF[m] = *(const bf16x8*)&SA[ra_ * 64 + (((KK) * 32 + fq * 8) ^ ((ra_ & 7) << 3))];   \
    }                                                                                        \
} while (0)

#define MFMA16(AF, BS, KK) do {                                                              \
    __builtin_amdgcn_s_setprio(1);                                                           \
    _Pragma("unroll")                                                                        \
    for (int m = 0; m < 4; ++m)                                                              \
        _Pragma("unroll")                                                                    \
        for (int n = 0; n < 4; ++n)                                                          \
            acc[m][n] = __builtin_amdgcn_mfma_f32_16x16x32_bf16(AF[m], BS[n * 2 + KK], acc[m][n], 0, 0, 0); \
    __builtin_amdgcn_s_setprio(0);                                                           \
} while (0)

// tile T: compute from (CA, BC); prefetch B(T+1)->BN (reg), stage A(T+2)->NA.
// boundary: vmcnt(2) = A(T+1)+B(T+1) drained, A(T+2) still in flight.
#define BODY(CA, NA, BC, BN, T) do {                                                         \
    bf16x8 af0[4], af1[4];                                                                   \
    RD_A(af0, CA, 0);                                                                        \
    RD_A(af1, CA, 1);                                                                        \
    __builtin_amdgcn_sched_barrier(0);                                                       \
    if ((T) <= 14) LD_B(BN, (T) + 1);                                                        \
    __builtin_amdgcn_sched_barrier(0);                                                       \
    if ((T) <= 13) STG_A(NA, (T) + 2);                                                       \
    __builtin_amdgcn_sched_barrier(0);                                                       \
    MFMA16(af0, BC, 0);                                                                      \
    MFMA16(af1, BC, 1);                                                                      \
    __builtin_amdgcn_sched_barrier(0);                                                       \
    if ((T) <= 13)       asm volatile("s_waitcnt vmcnt(2)" ::: "memory");                    \
    else if ((T) == 14)  asm volatile("s_waitcnt vmcnt(0)" ::: "memory");                    \
    if ((T) <= 14) __builtin_amdgcn_s_barrier();                                             \
    __builtin_amdgcn_sched_barrier(0);                                                       \
} while (0)

    // prologue: A(0)[2], B(0)[8], A(1)[2] issued in order; vmcnt(2) drains
    // A(0)+B(0), leaves A(1) in flight.
    STG_A(sA0, 0);
    __builtin_amdgcn_sched_barrier(0);
    LD_B(bSetA, 0);
    __builtin_amdgcn_sched_barrier(0);
    STG_A(sA1, 1);
    __builtin_amdgcn_sched_barrier(0);
    asm volatile("s_waitcnt vmcnt(2)" ::: "memory");
    __builtin_amdgcn_s_barrier();
    __builtin_amdgcn_sched_barrier(0);

    BODY(sA0, sA2, bSetA, bSetB, 0);
    BODY(sA1, sA0, bSetB, bSetA, 1);
    BODY(sA2, sA1, bSetA, bSetB, 2);
    BODY(sA0, sA2, bSetB, bSetA, 3);
    BODY(sA1, sA0, bSetA, bSetB, 4);
    BODY(sA2, sA1, bSetB, bSetA, 5);
    BODY(sA0, sA2, bSetA, bSetB, 6);
    BODY(sA1, sA0, bSetB, bSetA, 7);
    BODY(sA2, sA1, bSetA, bSetB, 8);
    BODY(sA0, sA2, bSetB, bSetA, 9);
    BODY(sA1, sA0, bSetA, bSetB, 10);
    BODY(sA2, sA1, bSetB, bSetA, 11);
    BODY(sA0, sA2, bSetA, bSetB, 12);
    BODY(sA1, sA0, bSetB, bSetA, 13);
    BODY(sA2, sA1, bSetA, bSetB, 14);
    BODY(sA0, sA2, bSetB, bSetA, 15);

#undef BODY
#undef MFMA16
#undef RD_A
#undef LD_B
#undef STG_A

    // epilogue: bias-select + tanh + bf16 store + partial logits
    // (all VMEM here is AFTER the loop; in-loop vmcnt counting stays exact)
    float u0v[4], u1v[4], wl0[4], wl1[4];
    int colg[4];
    #pragma unroll
    for (int n = 0; n < 4; ++n) {
        int c = colN + wc * 64 + n * 16 + fr;
        colg[n] = c;
        u0v[n] = u0[c]; u1v[n] = u1[c];
        wl0[n] = Wlin[c]; wl1[n] = Wlin[HID + c];
    }
    const int slot = blockIdx.y * 4 + wc;   // 16 slots

    #pragma unroll
    for (int m = 0; m < 4; ++m) {
        #pragma unroll
        for (int r = 0; r < 4; ++r) {
            long rowg = rowM + wr * 64 + m * 16 + fq * 4 + r;
            int bt = (words[rowg] >> sbit) & 1;
            float s0 = 0.f, s1 = 0.f;
            #pragma unroll
            for (int n = 0; n < 4; ++n) {
                float z  = acc[m][n][r] + (bt ? u1v[n] : u0v[n]);
                float hv = tanh_fast(z);
                hout[rowg * HID + colg[n]] = (bf16)hv;
                s0 += hv * wl0[n];
                s1 += hv * wl1[n];
            }
            #pragma unroll
            for (int off = 1; off < 16; off <<= 1) {
                s0 += __shfl_xor(s0, off, 16);
                s1 += __shfl_xor(s1, off, 16);
            }
            if (fr == 0)
                *(float2*)&plog_s[rowg * 32 + slot * 2] = make_float2(s0, s1);
        }
    }
}

// ---------------- finalize: softmax + permutation weights ----------------

__global__ void finalize(const float* __restrict__ plog, const float* __restrict__ l0s,
                         const float* __restrict__ blin, const unsigned int* __restrict__ words,
                         const float* __restrict__ fact, float* __restrict__ out) {
    long idx = (long)blockIdx.x * blockDim.x + threadIdx.x;
    if (idx >= (long)NSPIN * BATCH) return;
    int s = (int)(idx / BATCH), b = (int)(idx % BATCH);

    float l0, l1;
    if (s == 0) { l0 = l0s[0]; l1 = l0s[1]; }
    else {
        l0 = blin[0]; l1 = blin[1];
        const float* ps = plog + ((long)(s - 1) * BATCH + b) * 32;
        #pragma unroll
        for (int k = 0; k < 16; ++k) {
            l0 += ps[k * 2 + 0];
            l1 += ps[k * 2 + 1];
        }
    }
    float mx = fmaxf(l0, l1);
    float e0 = __expf(l0 - mx), e1 = __expf(l1 - mx);
    float p0 = e0 / (e0 + e1), p1 = e1 / (e0 + e1);
    if (s > 0) {
        const unsigned int wv = words[b];
        const int cd = __popc(wv & ((1u << s) - 1));
        const float cdf = (float)cd, cuf = (float)(s - cd);
        const float ku = 16.f - cuf, kd = 16.f - cdf;
        const int n = NSPIN - s;
        const int kui = (int)fminf(fmaxf(ku, 0.f), 32.f);
        const int kdi = (int)fminf(fmaxf(kd, 0.f), 32.f);
        const float wu = fact[n] / fact[kui] * (ku >= 0.f ? 1.f : 0.f) + 1e-12f;
        const float wd = fact[n] / fact[kdi] * (kd >= 0.f ? 1.f : 0.f) + 1e-12f;
        p0 *= wu; p1 *= wd;
    }
    float inv = 1.f / (p0 + p1);
    out[idx * 2 + 0] = p0 * inv;
    out[idx * 2 + 1] = p1 * inv;
}

// ---------------- launch ----------------

extern "C" void kernel_launch(void* const* d_in, const int* in_sizes, int n_in,
                              void* d_out, int out_size, void* d_ws, size_t ws_size,
                              hipStream_t stream) {
    const float* din  = (const float*)d_in[0];  // [32][8192][2]
    const float* Wih  = (const float*)d_in[1];  // [1024][2]
    const float* Whh  = (const float*)d_in[2];  // [1024][1024]
    const float* bih  = (const float*)d_in[3];  // [1024]
    const float* bhh  = (const float*)d_in[4];  // [1024]
    const float* Wlin = (const float*)d_in[5];  // [2][1024]
    const float* blin = (const float*)d_in[6];  // [2]
    float* out = (float*)d_out;

    char* ws = (char*)d_ws;
    size_t o = 0;
    auto alloc = [&](size_t b) { size_t r = o; o += (b + 255) & ~(size_t)255; return r; };
    bf16*  Wbf  = (bf16*)(ws + alloc((size_t)HID * HID * 2));
    float* u0   = (float*)(ws + alloc(HID * 4));
    float* u1   = (float*)(ws + alloc(HID * 4));
    bf16*  hrow = (bf16*)(ws + alloc(HID * 2));
    float* l0s  = (float*)(ws + alloc(2 * 4));
    float* fact = (float*)(ws + alloc(33 * 4));
    unsigned int* words = (unsigned int*)(ws + alloc((size_t)BATCH * 4));
    bf16*  hA   = (bf16*)(ws + alloc((size_t)BATCH * HID * 2));
    bf16*  hB   = (bf16*)(ws + alloc((size_t)BATCH * HID * 2));
    float* plog = (float*)(ws + alloc(31L * BATCH * 16 * 2 * 4));

    prep1<<<1024, 256, 0, stream>>>(din, Wih, Whh, bih, bhh, Wbf, u0, u1, words, fact);
    prep2<<<1, 1024, 0, stream>>>(u0, Wlin, blin, hrow, l0s);
    fillh<<<2048, 256, 0, stream>>>(hrow, hA);

    bf16* hin = hA; bf16* hout = hB;
    for (int s = 1; s <= 31; ++s) {
        gemm_step<<<dim3(64, 4), 512, 0, stream>>>(
            hin, hout, Wbf, u0, u1, words, s - 1, Wlin,
            plog + (size_t)(s - 1) * BATCH * 32);
        bf16* t = hin; hin = hout; hout = t;
    }
    finalize<<<(NSPIN * BATCH) / 256, 256, 0, stream>>>(plog, l0s, blin, words, fact, out);
}

// Round 12
// 872.582 us; speedup vs baseline: 1.6460x; 1.6460x over previous
//
#include <hip/hip_runtime.h>

// PositiveWaveFunction: 32-step tanh RNN, batch 8192, hidden 1024.
// R12: R11 (B in registers) with the gather made COALESCED: W is pre-packed
// into MFMA fragment order (panel/kt/frag/lane-contiguous 16B chunks), so
// each B-frag load is a 1KB coalesced burst from L2 (R11's 2KB-strided
// scatter wasted ~2x L2 line BW and starved MFMA -> 52us dispatches).
// A stays in the proven R7 3-buffer LDS rotation (XOR swizzle, counted
// vmcnt(2) boundaries). 8 waves = 2/SIMD covers load latency (R10 lesson).
// LDS/K-tile = 80KB (A only, -55% vs R7); B L2 traffic full-line-utilized.

typedef __bf16 bf16;
typedef __bf16 bf16x8 __attribute__((ext_vector_type(8)));
typedef float  f32x4  __attribute__((ext_vector_type(4)));

#define HID   1024
#define BATCH 8192
#define NSPIN 32

#define AS1 __attribute__((address_space(1)))
#define AS3 __attribute__((address_space(3)))

__device__ __forceinline__ float tanh_fast(float x) {
    float ax = fabsf(x);
    float t  = __expf(-2.0f * ax);                       // (0,1], no overflow
    float r  = (1.0f - t) * __builtin_amdgcn_rcpf(1.0f + t);
    return __builtin_copysignf(r, x);
}

// ---------------- prep kernels ----------------

__global__ void prep1(const float* __restrict__ din, const float* __restrict__ Wih,
                      const float* __restrict__ bih, const float* __restrict__ bhh,
                      float* __restrict__ u0, float* __restrict__ u1,
                      unsigned int* __restrict__ words, float* __restrict__ fact) {
    long idx = (long)blockIdx.x * blockDim.x + threadIdx.x;
    long stride = (long)gridDim.x * blockDim.x;
    for (long i = idx; i < HID; i += stride) {
        u0[i] = Wih[i * 2 + 0] + bih[i] + bhh[i];
        u1[i] = Wih[i * 2 + 1] + bih[i] + bhh[i];
    }
    for (long b = idx; b < BATCH; b += stride) {
        unsigned int wv = 0;
        for (int j = 0; j < 31; ++j)
            wv |= (din[((long)j * BATCH + b) * 2 + 1] != 0.0f ? 1u : 0u) << j;
        words[b] = wv;
    }
    if (idx == 0) {  // factorials: float64 cumprod cast to float32, like reference
        double f = 1.0; fact[0] = 1.0f;
        for (int k = 1; k <= NSPIN; ++k) { f *= k; fact[k] = (float)f; }
    }
}

// pack W_hh into MFMA fragment order:
// chunk c (16B = 8 bf16): l=c&63; j=(c>>6)&7 (j=n*2+kk); kt=(c>>9)&15; p=c>>13
// lane l=(fr=l&15, fq=l>>4) wants W[p*64 + n*16 + fr][kt*64 + kk*32 + fq*8 ..+8]
__global__ void prep_pack(const float* __restrict__ Whh, bf16* __restrict__ Wpack) {
    int c = blockIdx.x * blockDim.x + threadIdx.x;   // 0 .. 131071
    if (c >= 131072) return;
    const int l  = c & 63;
    const int j  = (c >> 6) & 7;
    const int kt = (c >> 9) & 15;
    const int p  = c >> 13;
    const int n  = j >> 1, kk = j & 1;
    const int col = p * 64 + n * 16 + (l & 15);
    const int k   = kt * 64 + kk * 32 + (l >> 4) * 8;
    const float* src = Whh + (long)col * HID + k;
    bf16* dst = Wpack + (long)c * 8;
    #pragma unroll
    for (int e = 0; e < 8; ++e) dst[e] = (bf16)src[e];
}

// single block: h after step 0 (identical for all batch rows) + its logits
__global__ void prep2(const float* __restrict__ u0, const float* __restrict__ Wlin,
                      const float* __restrict__ blin,
                      bf16* __restrict__ hrow, float* __restrict__ l0s) {
    __shared__ float red0[16], red1[16];
    int t = threadIdx.x;  // 0..1023
    float hv = tanh_fast(u0[t]);
    hrow[t] = (bf16)hv;
    float s0 = hv * Wlin[t], s1 = hv * Wlin[HID + t];
    #pragma unroll
    for (int off = 1; off < 64; off <<= 1) {
        s0 += __shfl_xor(s0, off, 64);
        s1 += __shfl_xor(s1, off, 64);
    }
    if ((t & 63) == 0) { red0[t >> 6] = s0; red1[t >> 6] = s1; }
    __syncthreads();
    if (t == 0) {
        float a = blin[0], b = blin[1];
        for (int i = 0; i < 16; ++i) { a += red0[i]; b += red1[i]; }
        l0s[0] = a; l0s[1] = b;
    }
}

// broadcast hrow to all 8192 rows of the ping buffer
__global__ void fillh(const bf16* __restrict__ hrow, bf16* __restrict__ hping) {
    const bf16x8* src = (const bf16x8*)hrow;   // 128 vectors per row
    bf16x8* dst = (bf16x8*)hping;
    long n8 = (long)BATCH * HID / 8;
    for (long v = (long)blockIdx.x * blockDim.x + threadIdx.x; v < n8;
         v += (long)gridDim.x * blockDim.x)
        dst[v] = src[v & 127];
}

// ---------------- main recurrence GEMM ----------------
// Z = h_in @ W_hh^T ; z += (bit ? u1 : u0) ; h_out = tanh(z) (bf16)
// partial logits per wave-column -> plog[31][8192][16][2]
// Tile 128x256, BK=64, 8 waves (2x4 of 64x64), 16x16x32 bf16 MFMA.
// A: LDS 3-buffer rotation (XOR swizzle, counted vmcnt). B: packed-W
// global->reg coalesced, double-set prefetch depth 1.

__global__ __launch_bounds__(512, 2) void gemm_step(
        const bf16* __restrict__ hin, bf16* __restrict__ hout,
        const bf16* __restrict__ Wpack,
        const float* __restrict__ u0, const float* __restrict__ u1,
        const unsigned int* __restrict__ words, int sbit,
        const float* __restrict__ Wlin,
        float* __restrict__ plog_s) {
    __shared__ __align__(16) bf16 sA0[128 * 64];
    __shared__ __align__(16) bf16 sA1[128 * 64];
    __shared__ __align__(16) bf16 sA2[128 * 64];

    const int tid = threadIdx.x;
    const int w = tid >> 6, l = tid & 63;
    const long rowM = (long)blockIdx.x * 128;
    const int  colN = blockIdx.y * 256;

    const int wr = w >> 2, wc = w & 3;      // 2x4 wave grid (64x64 tiles)
    const int fr = l & 15, fq = l >> 4;     // fragment lane coords

    f32x4 acc[4][4] = {};
    bf16x8 bSetA[8], bSetB[8];              // B frag double-set (n*2+kk)

    // staging lane decomposition: 8 rows x 8 chunks per issue
    const int lrow = l >> 3;                 // 0..7
    const int lchk = l & 7;                  // 0..7 (16B chunk)

    // packed-B lane base: panel p = blockIdx.y*4 + wc; lane-contiguous chunks
    const bf16* gBp = Wpack + ((long)(blockIdx.y * 4 + wc) * 65536) + l * 8;

// stage A rows (2 loads/wave, 8 waves cover 128 rows), source pre-permuted
// so linear LDS dest == XOR-swizzled layout
#define STG_A(SA, KT) do {                                                                   \
    _Pragma("unroll")                                                                        \
    for (int i = 0; i < 2; ++i) {                                                            \
        const int r_ = w * 16 + i * 8 + lrow;                                                \
        const int sc_ = (lchk ^ (r_ & 7)) * 8;                                               \
        __builtin_amdgcn_global_load_lds(                                                    \
            (const AS1 void*)(hin + (rowM + r_) * HID + (KT) * 64 + sc_),                    \
            (AS3 void*)(&SA[(w * 16 + i * 8) * 64]), 16, 0, 0);                              \
    }                                                                                        \
} while (0)

// B frags global->reg: 8 coalesced 1KB bursts (j = n*2+kk)
#define LD_B(BS, KT) do {                                                                    \
    _Pragma("unroll")                                                                        \
    for (int j = 0; j < 8; ++j)                                                              \
        BS[j] = *(const bf16x8*)(gBp + ((long)(KT) * 8 + j) * 512);                          \
} while (0)

#define RD_A(AF, SA, KK) do {                                                                \
    _Pragma("unroll")                                                                        \
    for (int m = 0; m < 4; ++m) {                                                            \
        const int ra_ = wr * 64 + m * 16 + fr;                                               \
        AF[m] = *(const bf16x8*)&SA[ra_ * 64 + (((KK) * 32 + fq * 8) ^ ((ra_ & 7) << 3))];   \
    }                                                                                        \
} while (0)

#define MFMA16(AF, BS, KK) do {                                                              \
    __builtin_amdgcn_s_setprio(1);                                                           \
    _Pragma("unroll")                                                                        \
    for (int m = 0; m < 4; ++m)                                                              \
        _Pragma("unroll")                                                                    \
        for (int n = 0; n < 4; ++n)                                                          \
            acc[m][n] = __builtin_amdgcn_mfma_f32_16x16x32_bf16(AF[m], BS[n * 2 + KK], acc[m][n], 0, 0, 0); \
    __builtin_amdgcn_s_setprio(0);                                                           \
} while (0)

// tile T: compute from (CA, BC); prefetch B(T+1)->BN (reg), stage A(T+2)->NA.
// boundary: vmcnt(2) = A(T+1)+B(T+1) drained, A(T+2) still in flight.
#define BODY(CA, NA, BC, BN, T) do {                                                         \
    bf16x8 af0[4], af1[4];                                                                   \
    RD_A(af0, CA, 0);                                                                        \
    RD_A(af1, CA, 1);                                                                        \
    __builtin_amdgcn_sched_barrier(0);                                                       \
    if ((T) <= 14) LD_B(BN, (T) + 1);                                                        \
    __builtin_amdgcn_sched_barrier(0);                                                       \
    if ((T) <= 13) STG_A(NA, (T) + 2);                                                       \
    __builtin_amdgcn_sched_barrier(0);                                                       \
    MFMA16(af0, BC, 0);                                                                      \
    MFMA16(af1, BC, 1);                                                                      \
    __builtin_amdgcn_sched_barrier(0);                                                       \
    if ((T) <= 13)       asm volatile("s_waitcnt vmcnt(2)" ::: "memory");                    \
    else if ((T) == 14)  asm volatile("s_waitcnt vmcnt(0)" ::: "memory");                    \
    if ((T) <= 14) __builtin_amdgcn_s_barrier();                                             \
    __builtin_amdgcn_sched_barrier(0);                                                       \
} while (0)

    // prologue: A(0)[2], B(0)[8], A(1)[2] issued in order; vmcnt(2) drains
    // A(0)+B(0), leaves A(1) in flight.
    STG_A(sA0, 0);
    __builtin_amdgcn_sched_barrier(0);
    LD_B(bSetA, 0);
    __builtin_amdgcn_sched_barrier(0);
    STG_A(sA1, 1);
    __builtin_amdgcn_sched_barrier(0);
    asm volatile("s_waitcnt vmcnt(2)" ::: "memory");
    __builtin_amdgcn_s_barrier();
    __builtin_amdgcn_sched_barrier(0);

    BODY(sA0, sA2, bSetA, bSetB, 0);
    BODY(sA1, sA0, bSetB, bSetA, 1);
    BODY(sA2, sA1, bSetA, bSetB, 2);
    BODY(sA0, sA2, bSetB, bSetA, 3);
    BODY(sA1, sA0, bSetA, bSetB, 4);
    BODY(sA2, sA1, bSetB, bSetA, 5);
    BODY(sA0, sA2, bSetA, bSetB, 6);
    BODY(sA1, sA0, bSetB, bSetA, 7);
    BODY(sA2, sA1, bSetA, bSetB, 8);
    BODY(sA0, sA2, bSetB, bSetA, 9);
    BODY(sA1, sA0, bSetA, bSetB, 10);
    BODY(sA2, sA1, bSetB, bSetA, 11);
    BODY(sA0, sA2, bSetA, bSetB, 12);
    BODY(sA1, sA0, bSetB, bSetA, 13);
    BODY(sA2, sA1, bSetA, bSetB, 14);
    BODY(sA0, sA2, bSetB, bSetA, 15);

#undef BODY
#undef MFMA16
#undef RD_A
#undef LD_B
#undef STG_A

    // epilogue: bias-select + tanh + bf16 store + partial logits
    // (all VMEM here is AFTER the loop; in-loop vmcnt counting stays exact)
    float u0v[4], u1v[4], wl0[4], wl1[4];
    int colg[4];
    #pragma unroll
    for (int n = 0; n < 4; ++n) {
        int c = colN + wc * 64 + n * 16 + fr;
        colg[n] = c;
        u0v[n] = u0[c]; u1v[n] = u1[c];
        wl0[n] = Wlin[c]; wl1[n] = Wlin[HID + c];
    }
    const int slot = blockIdx.y * 4 + wc;   // 16 slots

    #pragma unroll
    for (int m = 0; m < 4; ++m) {
        #pragma unroll
        for (int r = 0; r < 4; ++r) {
            long rowg = rowM + wr * 64 + m * 16 + fq * 4 + r;
            int bt = (words[rowg] >> sbit) & 1;
            float s0 = 0.f, s1 = 0.f;
            #pragma unroll
            for (int n = 0; n < 4; ++n) {
                float z  = acc[m][n][r] + (bt ? u1v[n] : u0v[n]);
                float hv = tanh_fast(z);
                hout[rowg * HID + colg[n]] = (bf16)hv;
                s0 += hv * wl0[n];
                s1 += hv * wl1[n];
            }
            #pragma unroll
            for (int off = 1; off < 16; off <<= 1) {
                s0 += __shfl_xor(s0, off, 16);
                s1 += __shfl_xor(s1, off, 16);
            }
            if (fr == 0)
                *(float2*)&plog_s[rowg * 32 + slot * 2] = make_float2(s0, s1);
        }
    }
}

// ---------------- finalize: softmax + permutation weights ----------------

__global__ void finalize(const float* __restrict__ plog, const float* __restrict__ l0s,
                         const float* __restrict__ blin, const unsigned int* __restrict__ words,
                         const float* __restrict__ fact, float* __restrict__ out) {
    long idx = (long)blockIdx.x * blockDim.x + threadIdx.x;
    if (idx >= (long)NSPIN * BATCH) return;
    int s = (int)(idx / BATCH), b = (int)(idx % BATCH);

    float l0, l1;
    if (s == 0) { l0 = l0s[0]; l1 = l0s[1]; }
    else {
        l0 = blin[0]; l1 = blin[1];
        const float* ps = plog + ((long)(s - 1) * BATCH + b) * 32;
        #pragma unroll
        for (int k = 0; k < 16; ++k) {
            l0 += ps[k * 2 + 0];
            l1 += ps[k * 2 + 1];
        }
    }
    float mx = fmaxf(l0, l1);
    float e0 = __expf(l0 - mx), e1 = __expf(l1 - mx);
    float p0 = e0 / (e0 + e1), p1 = e1 / (e0 + e1);
    if (s > 0) {
        const unsigned int wv = words[b];
        const int cd = __popc(wv & ((1u << s) - 1));
        const float cdf = (float)cd, cuf = (float)(s - cd);
        const float ku = 16.f - cuf, kd = 16.f - cdf;
        const int n = NSPIN - s;
        const int kui = (int)fminf(fmaxf(ku, 0.f), 32.f);
        const int kdi = (int)fminf(fmaxf(kd, 0.f), 32.f);
        const float wu = fact[n] / fact[kui] * (ku >= 0.f ? 1.f : 0.f) + 1e-12f;
        const float wd = fact[n] / fact[kdi] * (kd >= 0.f ? 1.f : 0.f) + 1e-12f;
        p0 *= wu; p1 *= wd;
    }
    float inv = 1.f / (p0 + p1);
    out[idx * 2 + 0] = p0 * inv;
    out[idx * 2 + 1] = p1 * inv;
}

// ---------------- launch ----------------

extern "C" void kernel_launch(void* const* d_in, const int* in_sizes, int n_in,
                              void* d_out, int out_size, void* d_ws, size_t ws_size,
                              hipStream_t stream) {
    const float* din  = (const float*)d_in[0];  // [32][8192][2]
    const float* Wih  = (const float*)d_in[1];  // [1024][2]
    const float* Whh  = (const float*)d_in[2];  // [1024][1024]
    const float* bih  = (const float*)d_in[3];  // [1024]
    const float* bhh  = (const float*)d_in[4];  // [1024]
    const float* Wlin = (const float*)d_in[5];  // [2][1024]
    const float* blin = (const float*)d_in[6];  // [2]
    float* out = (float*)d_out;

    char* ws = (char*)d_ws;
    size_t o = 0;
    auto alloc = [&](size_t b) { size_t r = o; o += (b + 255) & ~(size_t)255; return r; };
    bf16*  Wpack = (bf16*)(ws + alloc((size_t)HID * HID * 2));
    float* u0   = (float*)(ws + alloc(HID * 4));
    float* u1   = (float*)(ws + alloc(HID * 4));
    bf16*  hrow = (bf16*)(ws + alloc(HID * 2));
    float* l0s  = (float*)(ws + alloc(2 * 4));
    float* fact = (float*)(ws + alloc(33 * 4));
    unsigned int* words = (unsigned int*)(ws + alloc((size_t)BATCH * 4));
    bf16*  hA   = (bf16*)(ws + alloc((size_t)BATCH * HID * 2));
    bf16*  hB   = (bf16*)(ws + alloc((size_t)BATCH * HID * 2));
    float* plog = (float*)(ws + alloc(31L * BATCH * 16 * 2 * 4));

    prep1<<<256, 256, 0, stream>>>(din, Wih, bih, bhh, u0, u1, words, fact);
    prep_pack<<<512, 256, 0, stream>>>(Whh, Wpack);
    prep2<<<1, 1024, 0, stream>>>(u0, Wlin, blin, hrow, l0s);
    fillh<<<2048, 256, 0, stream>>>(hrow, hA);

    bf16* hin = hA; bf16* hout = hB;
    for (int s = 1; s <= 31; ++s) {
        gemm_step<<<dim3(64, 4), 512, 0, stream>>>(
            hin, hout, Wpack, u0, u1, words, s - 1, Wlin,
            plog + (size_t)(s - 1) * BATCH * 32);
        bf16* t = hin; hin = hout; hout = t;
    }
    finalize<<<(NSPIN * BATCH) / 256, 256, 0, stream>>>(plog, l0s, blin, words, fact, out);
}

// Round 13
// 600.351 us; speedup vs baseline: 2.3924x; 1.4535x over previous
//
#include <hip/hip_runtime.h>

// PositiveWaveFunction: 32-step tanh RNN, batch 8192, hidden 1024.
// R13: prefix-tree dedup. h after step s has only 2^s distinct values, so
// steps 1..13 run as tree levels on 2^(i-1) parent states (GEMM emits BOTH
// children z+u0 / z+u1): total tree work = 8191 rows ~= ONE full step,
// replacing 13 full-batch steps (~286us). Skinny 64x128-tile kernel keeps
// per-level latency low. After level 13: gather states->batch rows; steps
// 14..31 = exact R7 structure (763us proven; R12's B-in-reg reverted).
// Per-state logits -> slog (32 slots); finalize picks slog (s<=13, index
// p = brev(words & mask)) or plog (s>=14). fillh eliminated.

typedef __bf16 bf16;
typedef __bf16 bf16x8 __attribute__((ext_vector_type(8)));
typedef float  f32x4  __attribute__((ext_vector_type(4)));

#define HID   1024
#define BATCH 8192
#define NSPIN 32

#define AS1 __attribute__((address_space(1)))
#define AS3 __attribute__((address_space(3)))

__device__ __forceinline__ float tanh_fast(float x) {
    float ax = fabsf(x);
    float t  = __expf(-2.0f * ax);                       // (0,1], no overflow
    float r  = (1.0f - t) * __builtin_amdgcn_rcpf(1.0f + t);
    return __builtin_copysignf(r, x);
}

// ---------------- prep kernels ----------------

__global__ void prep1(const float* __restrict__ din, const float* __restrict__ Wih,
                      const float* __restrict__ Whh, const float* __restrict__ bih,
                      const float* __restrict__ bhh,
                      bf16* __restrict__ Wbf, float* __restrict__ u0, float* __restrict__ u1,
                      unsigned int* __restrict__ words, float* __restrict__ fact) {
    long idx = (long)blockIdx.x * blockDim.x + threadIdx.x;
    long stride = (long)gridDim.x * blockDim.x;
    for (long i = idx; i < (long)HID * HID; i += stride) Wbf[i] = (bf16)Whh[i];
    for (long i = idx; i < HID; i += stride) {
        u0[i] = Wih[i * 2 + 0] + bih[i] + bhh[i];
        u1[i] = Wih[i * 2 + 1] + bih[i] + bhh[i];
    }
    for (long b = idx; b < BATCH; b += stride) {
        unsigned int wv = 0;
        for (int j = 0; j < 31; ++j)
            wv |= (din[((long)j * BATCH + b) * 2 + 1] != 0.0f ? 1u : 0u) << j;
        words[b] = wv;
    }
    if (idx == 0) {  // factorials: float64 cumprod cast to float32, like reference
        double f = 1.0; fact[0] = 1.0f;
        for (int k = 1; k <= NSPIN; ++k) { f *= k; fact[k] = (float)f; }
    }
}

// single block: state0 = tanh(u0) (root of the tree) + its logits
__global__ void prep2(const float* __restrict__ u0, const float* __restrict__ Wlin,
                      const float* __restrict__ blin,
                      bf16* __restrict__ hrow, float* __restrict__ l0s) {
    __shared__ float red0[16], red1[16];
    int t = threadIdx.x;  // 0..1023
    float hv = tanh_fast(u0[t]);
    hrow[t] = (bf16)hv;
    float s0 = hv * Wlin[t], s1 = hv * Wlin[HID + t];
    #pragma unroll
    for (int off = 1; off < 64; off <<= 1) {
        s0 += __shfl_xor(s0, off, 64);
        s1 += __shfl_xor(s1, off, 64);
    }
    if ((t & 63) == 0) { red0[t >> 6] = s0; red1[t >> 6] = s1; }
    __syncthreads();
    if (t == 0) {
        float a = blin[0], b = blin[1];
        for (int i = 0; i < 16; ++i) { a += red0[i]; b += red1[i]; }
        l0s[0] = a; l0s[1] = b;
    }
}

// ---------------- tree level kernel ----------------
// hin: M parent states (rows). For each parent p: Z = h_p @ W^T (1024 cols);
// children 2p+bit = tanh(Z + u_bit), both written to hout; per-child logit
// partials (32 cols/wave) -> slog_s[child][32 slots][2].
// Block tile 64x128, 8 waves (2x4 of 32x32), BK=64, 3-buffer counted vmcnt.

__global__ __launch_bounds__(512, 2) void tree_step(
        const bf16* __restrict__ hin, bf16* __restrict__ hout,
        const bf16* __restrict__ Wbf,
        const float* __restrict__ u0, const float* __restrict__ u1,
        const float* __restrict__ Wlin,
        float* __restrict__ slog_s, int M) {
    __shared__ __align__(16) bf16 sA0[64 * 64];
    __shared__ __align__(16) bf16 sA1[64 * 64];
    __shared__ __align__(16) bf16 sA2[64 * 64];
    __shared__ __align__(16) bf16 sB0[128 * 64];
    __shared__ __align__(16) bf16 sB1[128 * 64];
    __shared__ __align__(16) bf16 sB2[128 * 64];

    const int tid = threadIdx.x;
    const int w = tid >> 6, l = tid & 63;
    const long rowM = (long)blockIdx.x * 64;
    const int  colN = blockIdx.y * 128;

    const int wr = w >> 2, wc = w & 3;      // 2x4 wave grid (32x32 tiles)
    const int fr = l & 15, fq = l >> 4;

    f32x4 acc[2][2] = {};

    const int lrow = l >> 3;                 // 0..7
    const int lchk = l & 7;                  // 0..7

#define TSTG(SA, SB, KT) do {                                                                \
    {   const int r_ = w * 8 + lrow;                                                         \
        const int sc_ = (lchk ^ (r_ & 7)) * 8;                                               \
        __builtin_amdgcn_global_load_lds(                                                    \
            (const AS1 void*)(hin + (rowM + r_) * HID + (KT) * 64 + sc_),                    \
            (AS3 void*)(&SA[(w * 8) * 64]), 16, 0, 0); }                                     \
    _Pragma("unroll")                                                                        \
    for (int i = 0; i < 2; ++i) {                                                            \
        const int r_ = w * 16 + i * 8 + lrow;                                                \
        const int sc_ = (lchk ^ (r_ & 7)) * 8;                                               \
        __builtin_amdgcn_global_load_lds(                                                    \
            (const AS1 void*)(Wbf + (long)(colN + r_) * HID + (KT) * 64 + sc_),              \
            (AS3 void*)(&SB[(w * 16 + i * 8) * 64]), 16, 0, 0);                              \
    }                                                                                        \
} while (0)

#define TBODY(CA, CB, NA, NB, T) do {                                                        \
    bf16x8 af[2][2], bf_[2][2];                                                              \
    _Pragma("unroll")                                                                        \
    for (int kk = 0; kk < 2; ++kk) {                                                         \
        _Pragma("unroll")                                                                    \
        for (int m = 0; m < 2; ++m) {                                                        \
            const int ra_ = wr * 32 + m * 16 + fr;                                           \
            af[kk][m] = *(const bf16x8*)&CA[ra_ * 64 + ((kk * 32 + fq * 8) ^ ((ra_ & 7) << 3))]; \
        }                                                                                    \
        _Pragma("unroll")                                                                    \
        for (int n = 0; n < 2; ++n) {                                                        \
            const int rb_ = wc * 32 + n * 16 + fr;                                           \
            bf_[kk][n] = *(const bf16x8*)&CB[rb_ * 64 + ((kk * 32 + fq * 8) ^ ((rb_ & 7) << 3))]; \
        }                                                                                    \
    }                                                                                        \
    if ((T) <= 13) TSTG(NA, NB, (T) + 2);                                                    \
    __builtin_amdgcn_s_setprio(1);                                                           \
    _Pragma("unroll")                                                                        \
    for (int kk = 0; kk < 2; ++kk)                                                           \
        _Pragma("unroll")                                                                    \
        for (int m = 0; m < 2; ++m)                                                          \
            _Pragma("unroll")                                                                \
            for (int n = 0; n < 2; ++n)                                                      \
                acc[m][n] = __builtin_amdgcn_mfma_f32_16x16x32_bf16(af[kk][m], bf_[kk][n], acc[m][n], 0, 0, 0); \
    __builtin_amdgcn_s_setprio(0);                                                           \
    __builtin_amdgcn_sched_barrier(0);                                                       \
    if ((T) <= 13)       asm volatile("s_waitcnt vmcnt(3)" ::: "memory");                    \
    else if ((T) == 14)  asm volatile("s_waitcnt vmcnt(0)" ::: "memory");                    \
    if ((T) <= 14) __builtin_amdgcn_s_barrier();                                             \
    __builtin_amdgcn_sched_barrier(0);                                                       \
} while (0)

    TSTG(sA0, sB0, 0);
    TSTG(sA1, sB1, 1);
    __builtin_amdgcn_sched_barrier(0);
    asm volatile("s_waitcnt vmcnt(3)" ::: "memory");
    __builtin_amdgcn_s_barrier();
    __builtin_amdgcn_sched_barrier(0);

    TBODY(sA0, sB0, sA2, sB2, 0);   TBODY(sA1, sB1, sA0, sB0, 1);
    TBODY(sA2, sB2, sA1, sB1, 2);   TBODY(sA0, sB0, sA2, sB2, 3);
    TBODY(sA1, sB1, sA0, sB0, 4);   TBODY(sA2, sB2, sA1, sB1, 5);
    TBODY(sA0, sB0, sA2, sB2, 6);   TBODY(sA1, sB1, sA0, sB0, 7);
    TBODY(sA2, sB2, sA1, sB1, 8);   TBODY(sA0, sB0, sA2, sB2, 9);
    TBODY(sA1, sB1, sA0, sB0, 10);  TBODY(sA2, sB2, sA1, sB1, 11);
    TBODY(sA0, sB0, sA2, sB2, 12);  TBODY(sA1, sB1, sA0, sB0, 13);
    TBODY(sA2, sB2, sA1, sB1, 14);  TBODY(sA0, sB0, sA2, sB2, 15);

#undef TBODY
#undef TSTG

    // epilogue: both children + logit partials
    float u0v[2], u1v[2], wl0[2], wl1[2];
    int colg[2];
    #pragma unroll
    for (int n = 0; n < 2; ++n) {
        int c = colN + wc * 32 + n * 16 + fr;
        colg[n] = c;
        u0v[n] = u0[c]; u1v[n] = u1[c];
        wl0[n] = Wlin[c]; wl1[n] = Wlin[HID + c];
    }
    const int slot = blockIdx.y * 4 + wc;   // 0..31

    #pragma unroll
    for (int m = 0; m < 2; ++m) {
        #pragma unroll
        for (int r = 0; r < 4; ++r) {
            long p = rowM + wr * 32 + m * 16 + fq * 4 + r;
            if (p < M) {
                float s00 = 0.f, s01 = 0.f, s10 = 0.f, s11 = 0.f;
                #pragma unroll
                for (int n = 0; n < 2; ++n) {
                    float z  = acc[m][n][r];
                    float h0 = tanh_fast(z + u0v[n]);
                    float h1 = tanh_fast(z + u1v[n]);
                    hout[(2 * p + 0) * HID + colg[n]] = (bf16)h0;
                    hout[(2 * p + 1) * HID + colg[n]] = (bf16)h1;
                    s00 += h0 * wl0[n]; s01 += h0 * wl1[n];
                    s10 += h1 * wl0[n]; s11 += h1 * wl1[n];
                }
                #pragma unroll
                for (int off = 1; off < 16; off <<= 1) {
                    s00 += __shfl_xor(s00, off, 16);
                    s01 += __shfl_xor(s01, off, 16);
                    s10 += __shfl_xor(s10, off, 16);
                    s11 += __shfl_xor(s11, off, 16);
                }
                if (fr == 0) {
                    *(float2*)&slog_s[(2 * p + 0) * 64 + slot * 2] = make_float2(s00, s01);
                    *(float2*)&slog_s[(2 * p + 1) * 64 + slot * 2] = make_float2(s10, s11);
                }
            }
        }
    }
}

// gather: h_batch[b] = states13[p13(b)]
__global__ void gatherh(const bf16* __restrict__ states, const unsigned int* __restrict__ words,
                        bf16* __restrict__ hbatch) {
    long v = (long)blockIdx.x * blockDim.x + threadIdx.x;
    const long total = (long)BATCH * 128;
    for (; v < total; v += (long)gridDim.x * blockDim.x) {
        int b = (int)(v >> 7), c = (int)(v & 127);
        unsigned int p = __brev(words[b] & 0x1FFFu) >> 19;
        ((bf16x8*)hbatch)[v] = ((const bf16x8*)states)[(long)p * 128 + c];
    }
}

// ---------------- full-batch GEMM step (exact R7 structure) ----------------
// Tile 128x256, BK=64, 8 waves (2x4 of 64x64). 3-buffer LDS (A+B staged),
// counted vmcnt(6) boundaries.

__global__ __launch_bounds__(512, 2) void gemm_step(
        const bf16* __restrict__ hin, bf16* __restrict__ hout,
        const bf16* __restrict__ Wbf,
        const float* __restrict__ u0, const float* __restrict__ u1,
        const unsigned int* __restrict__ words, int sbit,
        const float* __restrict__ Wlin,
        float* __restrict__ plog_s) {
    __shared__ __align__(16) bf16 sA0[128 * 64];
    __shared__ __align__(16) bf16 sA1[128 * 64];
    __shared__ __align__(16) bf16 sA2[128 * 64];
    __shared__ __align__(16) bf16 sB0[256 * 64];
    __shared__ __align__(16) bf16 sB1[256 * 64];
    __shared__ __align__(16) bf16 sB2[256 * 64];

    const int tid = threadIdx.x;
    const int w = tid >> 6, l = tid & 63;
    const long rowM = (long)blockIdx.x * 128;
    const int  colN = blockIdx.y * 256;

    const int wr = w >> 2, wc = w & 3;      // 2x4 wave grid (64x64 tiles)
    const int fr = l & 15, fq = l >> 4;     // fragment lane coords

    f32x4 acc[4][4] = {};

    const int lrow = l >> 3;                 // 0..7
    const int lchk = l & 7;                  // 0..7 (16B chunk)

#define STG_A(SA, KT) do {                                                                   \
    _Pragma("unroll")                                                                        \
    for (int i = 0; i < 2; ++i) {                                                            \
        const int r_ = w * 16 + i * 8 + lrow;                                                \
        const int sc_ = (lchk ^ (r_ & 7)) * 8;                                               \
        __builtin_amdgcn_global_load_lds(                                                    \
            (const AS1 void*)(hin + (rowM + r_) * HID + (KT) * 64 + sc_),                    \
            (AS3 void*)(&SA[(w * 16 + i * 8) * 64]), 16, 0, 0);                              \
    }                                                                                        \
} while (0)

#define STG_B2(SB, KT, I0) do {                                                              \
    _Pragma("unroll")                                                                        \
    for (int i = (I0); i < (I0) + 2; ++i) {                                                  \
        const int r_ = w * 32 + i * 8 + lrow;                                                \
        const int sc_ = (lchk ^ (r_ & 7)) * 8;                                               \
        __builtin_amdgcn_global_load_lds(                                                    \
            (const AS1 void*)(Wbf + (long)(colN + r_) * HID + (KT) * 64 + sc_),              \
            (AS3 void*)(&SB[(w * 32 + i * 8) * 64]), 16, 0, 0);                              \
    }                                                                                        \
} while (0)

#define RD_FRAGS(AF, BF, SA, SB, KK) do {                                                    \
    _Pragma("unroll")                                                                        \
    for (int m = 0; m < 4; ++m) {                                                            \
        const int ra_ = wr * 64 + m * 16 + fr;                                               \
        AF[m] = *(const bf16x8*)&SA[ra_ * 64 + (((KK) * 32 + fq * 8) ^ ((ra_ & 7) << 3))];   \
    }                                                                                        \
    _Pragma("unroll")                                                                        \
    for (int n = 0; n < 4; ++n) {                                                            \
        const int rb_ = wc * 64 + n * 16 + fr;                                               \
        BF[n] = *(const bf16x8*)&SB[rb_ * 64 + (((KK) * 32 + fq * 8) ^ ((rb_ & 7) << 3))];   \
    }                                                                                        \
} while (0)

#define MFMA16(AF, BF) do {                                                                  \
    __builtin_amdgcn_s_setprio(1);                                                           \
    _Pragma("unroll")                                                                        \
    for (int m = 0; m < 4; ++m)                                                              \
        _Pragma("unroll")                                                                    \
        for (int n = 0; n < 4; ++n)                                                          \
            acc[m][n] = __builtin_amdgcn_mfma_f32_16x16x32_bf16(AF[m], BF[n], acc[m][n], 0, 0, 0); \
    __builtin_amdgcn_s_setprio(0);                                                           \
} while (0)

#define BODY(CA, CB, NA, NB, T) do {                                                         \
    bf16x8 afx[4], bfx[4], afy[4], bfy[4];                                                   \
    RD_FRAGS(afx, bfx, CA, CB, 0);                                                           \
    if ((T) <= 13) { STG_A(NA, (T) + 2); STG_B2(NB, (T) + 2, 0); }                           \
    MFMA16(afx, bfx);                                                                        \
    RD_FRAGS(afy, bfy, CA, CB, 1);                                                           \
    if ((T) <= 13) { STG_B2(NB, (T) + 2, 2); }                                               \
    MFMA16(afy, bfy);                                                                        \
    __builtin_amdgcn_sched_barrier(0);                                                       \
    if ((T) <= 13)       asm volatile("s_waitcnt vmcnt(6)" ::: "memory");                    \
    else if ((T) == 14)  asm volatile("s_waitcnt vmcnt(0)" ::: "memory");                    \
    if ((T) <= 14) __builtin_amdgcn_s_barrier();                                             \
    __builtin_amdgcn_sched_barrier(0);                                                       \
} while (0)

    STG_A(sA0, 0); STG_B2(sB0, 0, 0); STG_B2(sB0, 0, 2);
    STG_A(sA1, 1); STG_B2(sB1, 1, 0); STG_B2(sB1, 1, 2);
    __builtin_amdgcn_sched_barrier(0);
    asm volatile("s_waitcnt vmcnt(6)" ::: "memory");
    __builtin_amdgcn_s_barrier();
    __builtin_amdgcn_sched_barrier(0);

    BODY(sA0, sB0, sA2, sB2, 0);
    BODY(sA1, sB1, sA0, sB0, 1);
    BODY(sA2, sB2, sA1, sB1, 2);
    BODY(sA0, sB0, sA2, sB2, 3);
    BODY(sA1, sB1, sA0, sB0, 4);
    BODY(sA2, sB2, sA1, sB1, 5);
    BODY(sA0, sB0, sA2, sB2, 6);
    BODY(sA1, sB1, sA0, sB0, 7);
    BODY(sA2, sB2, sA1, sB1, 8);
    BODY(sA0, sB0, sA2, sB2, 9);
    BODY(sA1, sB1, sA0, sB0, 10);
    BODY(sA2, sB2, sA1, sB1, 11);
    BODY(sA0, sB0, sA2, sB2, 12);
    BODY(sA1, sB1, sA0, sB0, 13);
    BODY(sA2, sB2, sA1, sB1, 14);
    BODY(sA0, sB0, sA2, sB2, 15);

#undef BODY
#undef MFMA16
#undef RD_FRAGS
#undef STG_A
#undef STG_B2

    // epilogue: bias-select + tanh + bf16 store + partial logits
    float u0v[4], u1v[4], wl0[4], wl1[4];
    int colg[4];
    #pragma unroll
    for (int n = 0; n < 4; ++n) {
        int c = colN + wc * 64 + n * 16 + fr;
        colg[n] = c;
        u0v[n] = u0[c]; u1v[n] = u1[c];
        wl0[n] = Wlin[c]; wl1[n] = Wlin[HID + c];
    }
    const int slot = blockIdx.y * 4 + wc;   // 16 slots

    #pragma unroll
    for (int m = 0; m < 4; ++m) {
        #pragma unroll
        for (int r = 0; r < 4; ++r) {
            long rowg = rowM + wr * 64 + m * 16 + fq * 4 + r;
            int bt = (words[rowg] >> sbit) & 1;
            float s0 = 0.f, s1 = 0.f;
            #pragma unroll
            for (int n = 0; n < 4; ++n) {
                float z  = acc[m][n][r] + (bt ? u1v[n] : u0v[n]);
                float hv = tanh_fast(z);
                hout[rowg * HID + colg[n]] = (bf16)hv;
                s0 += hv * wl0[n];
                s1 += hv * wl1[n];
            }
            #pragma unroll
            for (int off = 1; off < 16; off <<= 1) {
                s0 += __shfl_xor(s0, off, 16);
                s1 += __shfl_xor(s1, off, 16);
            }
            if (fr == 0)
                *(float2*)&plog_s[rowg * 32 + slot * 2] = make_float2(s0, s1);
        }
    }
}

// ---------------- finalize: softmax + permutation weights ----------------

__global__ void finalize(const float* __restrict__ plog, const float* __restrict__ slog,
                         const float* __restrict__ l0s,
                         const float* __restrict__ blin, const unsigned int* __restrict__ words,
                         const float* __restrict__ fact, float* __restrict__ out) {
    long idx = (long)blockIdx.x * blockDim.x + threadIdx.x;
    if (idx >= (long)NSPIN * BATCH) return;
    int s = (int)(idx / BATCH), b = (int)(idx % BATCH);
    const unsigned int wv = words[b];

    float l0, l1;
    if (s == 0) { l0 = l0s[0]; l1 = l0s[1]; }
    else if (s <= 13) {
        unsigned int p = __brev(wv & ((1u << s) - 1)) >> (32 - s);
        const float* ps = slog + ((long)((1u << s) - 2) + p) * 64;
        l0 = blin[0]; l1 = blin[1];
        #pragma unroll
        for (int k = 0; k < 32; ++k) {
            l0 += ps[k * 2 + 0];
            l1 += ps[k * 2 + 1];
        }
    } else {
        l0 = blin[0]; l1 = blin[1];
        const float* ps = plog + ((long)(s - 14) * BATCH + b) * 32;
        #pragma unroll
        for (int k = 0; k < 16; ++k) {
            l0 += ps[k * 2 + 0];
            l1 += ps[k * 2 + 1];
        }
    }
    float mx = fmaxf(l0, l1);
    float e0 = __expf(l0 - mx), e1 = __expf(l1 - mx);
    float p0 = e0 / (e0 + e1), p1 = e1 / (e0 + e1);
    if (s > 0) {
        const int cd = __popc(wv & ((1u << s) - 1));
        const float cdf = (float)cd, cuf = (float)(s - cd);
        const float ku = 16.f - cuf, kd = 16.f - cdf;
        const int n = NSPIN - s;
        const int kui = (int)fminf(fmaxf(ku, 0.f), 32.f);
        const int kdi = (int)fminf(fmaxf(kd, 0.f), 32.f);
        const float wu = fact[n] / fact[kui] * (ku >= 0.f ? 1.f : 0.f) + 1e-12f;
        const float wd = fact[n] / fact[kdi] * (kd >= 0.f ? 1.f : 0.f) + 1e-12f;
        p0 *= wu; p1 *= wd;
    }
    float inv = 1.f / (p0 + p1);
    out[idx * 2 + 0] = p0 * inv;
    out[idx * 2 + 1] = p1 * inv;
}

// ---------------- launch ----------------

extern "C" void kernel_launch(void* const* d_in, const int* in_sizes, int n_in,
                              void* d_out, int out_size, void* d_ws, size_t ws_size,
                              hipStream_t stream) {
    const float* din  = (const float*)d_in[0];  // [32][8192][2]
    const float* Wih  = (const float*)d_in[1];  // [1024][2]
    const float* Whh  = (const float*)d_in[2];  // [1024][1024]
    const float* bih  = (const float*)d_in[3];  // [1024]
    const float* bhh  = (const float*)d_in[4];  // [1024]
    const float* Wlin = (const float*)d_in[5];  // [2][1024]
    const float* blin = (const float*)d_in[6];  // [2]
    float* out = (float*)d_out;

    char* ws = (char*)d_ws;
    size_t o = 0;
    auto alloc = [&](size_t b) { size_t r = o; o += (b + 255) & ~(size_t)255; return r; };
    bf16*  Wbf  = (bf16*)(ws + alloc((size_t)HID * HID * 2));
    float* u0   = (float*)(ws + alloc(HID * 4));
    float* u1   = (float*)(ws + alloc(HID * 4));
    bf16*  hrow = (bf16*)(ws + alloc((size_t)64 * HID * 2));   // 64-row padded root
    float* l0s  = (float*)(ws + alloc(2 * 4));
    float* fact = (float*)(ws + alloc(33 * 4));
    unsigned int* words = (unsigned int*)(ws + alloc((size_t)BATCH * 4));
    bf16*  hA   = (bf16*)(ws + alloc((size_t)BATCH * HID * 2));
    bf16*  hB   = (bf16*)(ws + alloc((size_t)BATCH * HID * 2));
    float* slog = (float*)(ws + alloc(((size_t)(1 << 14) - 2) * 64 * 4));  // ~4.2 MB
    float* plog = (float*)(ws + alloc(18L * BATCH * 32 * 4));              // 18.9 MB

    prep1<<<1024, 256, 0, stream>>>(din, Wih, Whh, bih, bhh, Wbf, u0, u1, words, fact);
    prep2<<<1, 1024, 0, stream>>>(u0, Wlin, blin, hrow, l0s);

    // tree levels: level i consumes 2^(i-1) states, emits 2^i (states at step i)
    const bf16* tin = hrow;
    bf16* tout = hA;
    for (int i = 1; i <= 13; ++i) {
        int Min = 1 << (i - 1);
        dim3 g(Min < 64 ? 1 : Min / 64, 8);
        tree_step<<<g, 512, 0, stream>>>(
            tin, tout, Wbf, u0, u1, Wlin,
            slog + ((long)(1 << i) - 2) * 64, Min);
        tin = tout;
        tout = (tout == hA) ? hB : hA;
    }
    // tin = states13 (hA); tout = hB
    gatherh<<<2048, 256, 0, stream>>>(tin, words, tout);   // hB = batch h13

    bf16* hin = tout;                       // hB
    bf16* hout = (tout == hA) ? hB : hA;    // hA
    for (int s = 14; s <= 31; ++s) {
        gemm_step<<<dim3(64, 4), 512, 0, stream>>>(
            hin, hout, Wbf, u0, u1, words, s - 1, Wlin,
            plog + (size_t)(s - 14) * BATCH * 32);
        bf16* t = hin; hin = hout; hout = t;
    }
    finalize<<<(NSPIN * BATCH) / 256, 256, 0, stream>>>(plog, slog, l0s, blin, words, fact, out);
}